// Round 9
// baseline (27684.573 us; speedup 1.0000x reference)
//
#include <hip/hip_runtime.h>
#include <cstdint>

// ---------------- configuration ----------------
#define HDIM 250          // hidden size
#define GDIM 1000         // 4*H gate rows
#define CH   64           // chunk length (steps) for inter-WG handoff
#define PP   4            // projection WGs per layer-ring
#define NW   4            // recurrent workers per layer (unit-split, 64/64/64/58)
#define HRING 4           // h ring depth (chunks)
#define XRING 4           // xw ring depth (chunks)
#define RPAD 1024         // padded gate-row dimension
#define NTH  1024

// rec-role LDS: 2 weight quads/thread (32KB) | h dbuf (skewed) | reduce
#define HSEG 144
#define HBUF (4 * HSEG)                     // 576 B per parity
#define HB_BASE 32768
#define RED_BASE (HB_BASE + 2 * HBUF)       // 33920
#define SMEM_BYTES 92160                    // 90 KB -> 1 WG/CU (proj needs 66KB)

typedef _Float16 f16x2 __attribute__((ext_vector_type(2)));

__device__ __forceinline__ float fdot2u(uint32_t w, uint32_t h, float acc) {
#if defined(__has_builtin) && __has_builtin(__builtin_amdgcn_fdot2)
  return __builtin_amdgcn_fdot2(__builtin_bit_cast(f16x2, w),
                                __builtin_bit_cast(f16x2, h), acc, false);
#else
  f16x2 wv = __builtin_bit_cast(f16x2, w), hv = __builtin_bit_cast(f16x2, h);
  return acc + (float)wv[0] * (float)hv[0] + (float)wv[1] * (float)hv[1];
#endif
}

__device__ __forceinline__ uint32_t pkh2(float a, float b) {
  f16x2 p; p[0] = (_Float16)a; p[1] = (_Float16)b;
  return __builtin_bit_cast(uint32_t, p);
}

// pack 8 consecutive f32 weights (zero beyond HDIM / null row) into 4x fp16x2
__device__ __forceinline__ uint4 pack8q(const float* rp, int c0) {
  float c[8];
#pragma unroll
  for (int u = 0; u < 8; ++u) {
    int col = c0 + u;
    c[u] = (rp && col < HDIM) ? rp[col] : 0.f;
  }
  uint4 r;
  r.x = pkh2(c[0], c[1]); r.y = pkh2(c[2], c[3]);
  r.z = pkh2(c[4], c[5]); r.w = pkh2(c[6], c[7]);
  return r;
}

__device__ __forceinline__ float rcpf_(float x) {
#if defined(__has_builtin) && __has_builtin(__builtin_amdgcn_rcpf)
  return __builtin_amdgcn_rcpf(x);
#else
  return 1.f / x;
#endif
}
__device__ __forceinline__ float sigm(float x) {
  return rcpf_(1.f + exp2f(-1.44269504088896341f * x));
}
__device__ __forceinline__ float tanh_(float x) {
  float e = exp2f(2.88539008177792681f * x);
  return 1.f - 2.f * rcpf_(e + 1.f);
}

// DPP quad_perm: 0xB1 = swap lane^1, 0x4E = swap lane^2 (within quads)
template <int CTRL>
__device__ __forceinline__ float dppq(float v) {
  return __builtin_bit_cast(
      float, __builtin_amdgcn_update_dpp(0, __builtin_bit_cast(int, v), CTRL,
                                         0xF, 0xF, true));
}
// ds_swizzle xor-lane within 32-lane group (BitMode offset)
template <int IMM>
__device__ __forceinline__ float swz(float v) {
  return __builtin_bit_cast(
      float, __builtin_amdgcn_ds_swizzle(__builtin_bit_cast(int, v), IMM));
}

__device__ __forceinline__ void step_barrier() {
  asm volatile("s_waitcnt lgkmcnt(0)\n\ts_barrier" ::: "memory");
}

// ---------------- flags (ints, in d_ws, zeroed each launch) ----------------
#define F_HCNTW(F, li, w)  (F)[(li) * 4 + (w)]          // h chunks produced
#define F_XWCONW(F, li, w) (F)[8 + (li) * 4 + (w)]      // xw chunks consumed
#define F_HDONE(F, li, p)  (F)[16 + (li) * 4 + (p)]     // proj staged chunk
#define F_XWRDY(F, li, c)  (F)[32 + (li) * 128 + (c)]   // xw chunk ready
#define F_HXC(F, L, w)     (F)[512 + (L) * 4 + (w)]     // per-step h counter

__device__ __forceinline__ int aload(int* p) {
  return __hip_atomic_load(p, __ATOMIC_RELAXED, __HIP_MEMORY_SCOPE_AGENT);
}
__device__ __forceinline__ void arel(int* p, int v) {
  __hip_atomic_store(p, v, __ATOMIC_RELEASE, __HIP_MEMORY_SCOPE_AGENT);
}
__device__ __forceinline__ void acq_fence() {
  __builtin_amdgcn_fence(__ATOMIC_ACQUIRE, "agent");
}
__device__ __forceinline__ void spin_ge(int* p, int tgt) {
  unsigned n = 0;
  while (aload(p) < tgt) {
    __builtin_amdgcn_s_sleep(2);
    if (++n > 100000000u) return;  // hang guard; result will fail visibly
  }
}

// ---------------- init: transpose Wih1/2 -> WT[li][j][RPAD], biases ----------------
__global__ void lstm_init(const float* __restrict__ Wih1, const float* __restrict__ bih1,
                          const float* __restrict__ bhh1, const float* __restrict__ Wih2,
                          const float* __restrict__ bih2, const float* __restrict__ bhh2,
                          float* __restrict__ WT, float* __restrict__ BV) {
  int idx = blockIdx.x * blockDim.x + threadIdx.x;
  int stride = gridDim.x * blockDim.x;
  for (int i = idx; i < 2 * HDIM * RPAD; i += stride) {
    int li = i / (HDIM * RPAD);
    int rem = i - li * HDIM * RPAD;
    int j = rem / RPAD, r = rem - j * RPAD;
    const float* W = li ? Wih2 : Wih1;
    WT[i] = (r < GDIM) ? W[r * HDIM + j] : 0.f;
  }
  for (int i = idx; i < 2 * RPAD; i += stride) {
    int li = i >> 10, r = i & 1023;
    const float* bi = li ? bih2 : bih1;
    const float* bh = li ? bhh2 : bhh1;
    BV[i] = (r < GDIM) ? bi[r] + bh[r] : 0.f;
  }
}

// ---------------- main persistent kernel ----------------
// blocks 0..11 : recurrent workers. L = bid/4, w = bid%4. Worker owns units
//   [64w, 64w+64) (58 for w=3): 256 rows x 250 cols fp16 = 128KB:
//   thread = row rr(=tid>>2) x 64-col slice sl(=tid&3): 8 quads =
//   6 named VGPR quads + 2 LDS quads (fits the observed 64-VGPR budget).
//   Cross-worker h exchange per step via L2 (hx buffer + per-worker counters).
// blocks 12..19: projection WGs (xw ring for layers 1,2).
__global__ void __launch_bounds__(NTH) lstm_main(
    const float* __restrict__ x, const float* __restrict__ Wih0,
    const float* __restrict__ bih0, const float* __restrict__ bhh0,
    const float* __restrict__ Whh0, const float* __restrict__ Whh1,
    const float* __restrict__ Whh2, const float* __restrict__ Wl,
    const float* __restrict__ bl, int* __restrict__ F, float* __restrict__ hx,
    const float* __restrict__ WT, const float* __restrict__ BV,
    float* __restrict__ hRing, float* __restrict__ xwRing,
    float* __restrict__ out, int T) {
  __shared__ __align__(16) char smem[SMEM_BYTES];
  const int tid = threadIdx.x;
  const int bid = blockIdx.x;
  const int NC = T / CH;

  if (bid < 12) {
    // ================= recurrent worker =================
    const int L = bid >> 2, w = bid & 3;
    const int sl = tid & 3;            // 64-col slice
    const int gate = (tid >> 2) & 3;   // gate row within unit
    const int lu = tid >> 4;           // local unit 0..63
    const int UW = (w < 3) ? 64 : 58;  // units this worker owns
    const int u_glob = w * 64 + lu;
    const bool uok = (lu < UW);
    const bool lead = ((tid & 15) == 0) && uok;
    const int r_abs = gate * HDIM + u_glob;  // global gate row

    const float* Whh = (L == 0) ? Whh0 : (L == 1) ? Whh1 : Whh2;
    const float* rp = uok ? (Whh + (size_t)r_abs * HDIM) : (const float*)nullptr;
    char* lw = smem + tid * 16;
#define LW(q) (lw + (size_t)(q) * (NTH * 16))

    // 8 weight quads for this row's 64-col slice: 6 in regs, 2 in LDS
    uint4 q0 = pack8q(rp, sl * 64 + 0);
    uint4 q1 = pack8q(rp, sl * 64 + 8);
    uint4 q2 = pack8q(rp, sl * 64 + 16);
    uint4 q3 = pack8q(rp, sl * 64 + 24);
    uint4 q4 = pack8q(rp, sl * 64 + 32);
    uint4 q5 = pack8q(rp, sl * 64 + 40);
    *(uint4*)LW(0) = pack8q(rp, sl * 64 + 48);
    *(uint4*)LW(1) = pack8q(rp, sl * 64 + 56);

    // L0 input-projection scalars
    float w0_ = 0.f, b0_ = 0.f;
    if (L == 0 && uok) {
      w0_ = Wih0[r_abs];
      b0_ = bih0[r_abs] + bhh0[r_abs];
    }

    // loader duty: stage 3 remote h chunks (f32 pairs -> packed fp16 LDS)
    const int lt = tid - 768;
    int cw = -1, li2 = 0;
    bool loader = false;
    if (lt >= 0 && lt < 96) {
      int idx = lt >> 5;
      li2 = lt & 31;
      cw = idx + (idx >= w ? 1 : 0);
      loader = li2 < ((cw == 3) ? 29 : 32);
    }

    // zero h double-buffer (incl. pad cols)
    for (int i = tid; i < (2 * HBUF) / 4; i += NTH)
      *(uint32_t*)(smem + HB_BASE + 4 * i) = 0u;
    __syncthreads();

    const float* xwBase = xwRing + (size_t)(L > 0 ? L - 1 : 0) * XRING * CH * RPAD;
    float* hBase = hRing + (size_t)L * HRING * CH * HDIM;
    float c_st = 0.f;

    for (int tt = 0; tt < T; ++tt) {
      const int tc = tt & (CH - 1);
      const int c = tt >> 6;
      const int p = tt & 1, ns = p ^ 1;
      if (tc == 0) {  // chunk boundary: input ready / ring backpressure
        if (tid == 0) {
          if (L > 0) spin_ge(&F_XWRDY(F, L - 1, c), 1);
          if (L < 2 && c >= HRING) {
            int cc = c - HRING;
            spin_ge(&F_HDONE(F, L, cc % PP), cc + 1);
          }
          acq_fence();
        }
        __syncthreads();
      }

      // gate input for this row (VMEM early, used after the dot)
      float xw = 0.f;
      if (uok) {
        if (L == 0) {
          xw = fmaf(x[tt], w0_, b0_);
        } else {
          const float* xp = xwBase + (size_t)(c & (XRING - 1)) * CH * RPAD +
                            (size_t)tc * RPAD;
          xw = xp[r_abs];
        }
      }

      // dot: 1 row x 64-col slice from skewed h buffer parity p
      const char* hbp = smem + HB_BASE + p * HBUF + sl * HSEG;
      float a = 0.f;
#define FD4(W_, H_)                  \
  a = fdot2u((W_).x, (H_).x, a);     \
  a = fdot2u((W_).y, (H_).y, a);     \
  a = fdot2u((W_).z, (H_).z, a);     \
  a = fdot2u((W_).w, (H_).w, a);
      { uint4 hq = *(const uint4*)(hbp + 0);  FD4(q0, hq) }
      { uint4 hq = *(const uint4*)(hbp + 16); FD4(q1, hq) }
      { uint4 hq = *(const uint4*)(hbp + 32); FD4(q2, hq) }
      { uint4 hq = *(const uint4*)(hbp + 48); FD4(q3, hq) }
      { uint4 hq = *(const uint4*)(hbp + 64); FD4(q4, hq) }
      { uint4 hq = *(const uint4*)(hbp + 80); FD4(q5, hq) }
      { uint4 hq = *(const uint4*)(hbp + 96);  uint4 t6 = *(const uint4*)LW(0); FD4(t6, hq) }
      { uint4 hq = *(const uint4*)(hbp + 112); uint4 t7 = *(const uint4*)LW(1); FD4(t7, hq) }

      // reduce over the 4 col-slices (quad butterfly), add xw
      a += dppq<0xB1>(a);
      a += dppq<0x4E>(a);
      a += xw;

      // gather the 4 gates of this unit (xor 4/8/12 within 16-lane group)
      float v4 = swz<0x101F>(a);
      float v8 = swz<0x201F>(a);
      float vc = swz<0x301F>(a);
      const float gi = (gate == 0) ? a : (gate == 1) ? v4 : (gate == 2) ? v8 : vc;
      const float gf = ((gate ^ 1) == 0) ? a : ((gate ^ 1) == 1) ? v4 : ((gate ^ 1) == 2) ? v8 : vc;
      const float gG = ((gate ^ 2) == 0) ? a : ((gate ^ 2) == 1) ? v4 : ((gate ^ 2) == 2) ? v8 : vc;
      const float go = ((gate ^ 3) == 0) ? a : ((gate ^ 3) == 1) ? v4 : ((gate ^ 3) == 2) ? v8 : vc;

      // LSTM update (redundant in all 16 lanes of the unit group)
      const float ii = sigm(gi), ff = sigm(gf), tg = tanh_(gG), oo = sigm(go);
      c_st = ff * c_st + ii * tg;
      const float hn = oo * tanh_(c_st);

      // publish own units: hRing (proj) + hx (remote workers)
      if (lead) {
        if (L < 2)
          hBase[(size_t)(c & (HRING - 1)) * CH * HDIM + (size_t)tc * HDIM + u_glob] = hn;
        __hip_atomic_store((uint32_t*)&hx[(L * 2 + ns) * 256 + u_glob],
                           __builtin_bit_cast(uint32_t, hn), __ATOMIC_RELAXED,
                           __HIP_MEMORY_SCOPE_AGENT);
      }
      asm volatile("s_waitcnt vmcnt(0)" ::: "memory");
      __syncthreads();
      if (tid == 0) {
        arel(&F_HXC(F, L, w), tt + 1);
        if (tc == CH - 1) {
          if (L < 2) arel(&F_HCNTW(F, L, w), c + 1);
          if (L > 0) arel(&F_XWCONW(F, L - 1, w), c + 1);
        }
      }

      // stage h(t) into parity ns: local direct, remote via hx
      if (lead)
        *(_Float16*)(smem + HB_BASE + ns * HBUF + (u_glob >> 6) * HSEG +
                     (u_glob & 63) * 2) = (_Float16)hn;
      if (loader) {
        spin_ge(&F_HXC(F, L, cw), tt + 1);
        acq_fence();
        const float2 hv = *(const float2*)&hx[(L * 2 + ns) * 256 + 64 * cw + 2 * li2];
        *(uint32_t*)(smem + HB_BASE + ns * HBUF + cw * HSEG + 4 * li2) =
            pkh2(hv.x, hv.y);
      }
      step_barrier();
    }

    if (L == 2 && w == 0) {  // final linear on full h(T-1) (in LDS, parity T&1)
      float* red = (float*)(smem + RED_BASE);
      const int pT = T & 1;
      if (tid < HDIM) {
        float hv = (float)*(_Float16*)(smem + HB_BASE + pT * HBUF +
                                       (tid >> 6) * HSEG + (tid & 63) * 2);
        red[tid] = hv * Wl[tid];
      }
      __syncthreads();
      if (tid == 0) {
        float s = bl[0];
        for (int j = 0; j < HDIM; ++j) s += red[j];
        out[0] = s;
      }
    }
  } else {
    // ================= projection role =================
    const int li = (bid - 12) / PP;
    const int p = (bid - 12) % PP;
    float* ldsH = (float*)smem;  // [64][257] f32
    const int lane = tid & 63, wid = tid >> 6;
    const float* WTl = WT + (size_t)li * HDIM * RPAD;
    const float* BVl = BV + (size_t)li * RPAD;

    for (int c = p; c < NC; c += PP) {
      if (tid == 0) {
        for (int ww = 0; ww < NW; ++ww) spin_ge(&F_HCNTW(F, li, ww), c + 1);
        if (c >= XRING)
          for (int ww = 0; ww < NW; ++ww)
            spin_ge(&F_XWCONW(F, li, ww), c - XRING + 1);
        acq_fence();
      }
      __syncthreads();
      const float* hsrc = hRing + (size_t)li * HRING * CH * HDIM +
                          (size_t)(c & (HRING - 1)) * CH * HDIM;
      for (int t = wid; t < CH; t += 16)
        for (int j = lane; j < HDIM; j += 64)
          ldsH[t * 257 + j] = hsrc[t * HDIM + j];
      __syncthreads();
      if (tid == 0) arel(&F_HDONE(F, li, p), c + 1);

      float* xdst = xwRing + (size_t)li * XRING * CH * RPAD +
                    (size_t)(c & (XRING - 1)) * CH * RPAD;
      const int rb0 = wid * 64;  // 16 waves x 64 rows
      for (int grpq = 0; grpq < 8; ++grpq) {
        const int rb = rb0 + grpq * 8;
        float acc[8];
#pragma unroll
        for (int uq = 0; uq < 8; ++uq) acc[uq] = 0.f;
        const float* wp = WTl + rb;
        float4 wa4 = *(const float4*)(wp);
        float4 wb4 = *(const float4*)(wp + 4);
        for (int j = 0; j < HDIM; ++j) {
          int jn = (j + 1 < HDIM) ? j + 1 : HDIM - 1;
          float4 na = *(const float4*)(wp + (size_t)jn * RPAD);
          float4 nb = *(const float4*)(wp + (size_t)jn * RPAD + 4);
          float hj = ldsH[lane * 257 + j];
          acc[0] = fmaf(wa4.x, hj, acc[0]); acc[1] = fmaf(wa4.y, hj, acc[1]);
          acc[2] = fmaf(wa4.z, hj, acc[2]); acc[3] = fmaf(wa4.w, hj, acc[3]);
          acc[4] = fmaf(wb4.x, hj, acc[4]); acc[5] = fmaf(wb4.y, hj, acc[5]);
          acc[6] = fmaf(wb4.z, hj, acc[6]); acc[7] = fmaf(wb4.w, hj, acc[7]);
          wa4 = na; wb4 = nb;
        }
#pragma unroll
        for (int uq = 0; uq < 8; ++uq) {
          int r = rb + uq;
          if (r < GDIM) xdst[(size_t)lane * RPAD + r] = acc[uq] + BVl[r];
        }
      }
      __syncthreads();
      if (tid == 0) arel(&F_XWRDY(F, li, c), 1);
    }
  }
}

// ---------------- launch ----------------
extern "C" void kernel_launch(void* const* d_in, const int* in_sizes, int n_in,
                              void* d_out, int out_size, void* d_ws, size_t ws_size,
                              hipStream_t stream) {
  const float* x    = (const float*)d_in[0];
  const float* Wih0 = (const float*)d_in[1];
  const float* Whh0 = (const float*)d_in[2];
  const float* bih0 = (const float*)d_in[3];
  const float* bhh0 = (const float*)d_in[4];
  const float* Wih1 = (const float*)d_in[5];
  const float* Whh1 = (const float*)d_in[6];
  const float* bih1 = (const float*)d_in[7];
  const float* bhh1 = (const float*)d_in[8];
  const float* Wih2 = (const float*)d_in[9];
  const float* Whh2 = (const float*)d_in[10];
  const float* bih2 = (const float*)d_in[11];
  const float* bhh2 = (const float*)d_in[12];
  const float* Wl   = (const float*)d_in[13];
  const float* bl   = (const float*)d_in[14];
  const int T = in_sizes[0];

  char* ws = (char*)d_ws;
  int*   F   = (int*)ws;                                  // 4096 B flags
  float* hx  = (float*)(ws + 4096);                       // 6144 B h exchange
  float* WT  = (float*)(ws + 12288);                      // 2,048,000 B
  float* BV  = (float*)(ws + 12288 + 2048000);            // 8,192 B
  float* hR  = (float*)(ws + 12288 + 2048000 + 8192);     // 512,000 B
  float* xwR = (float*)(ws + 12288 + 2048000 + 8192 + 512000);  // 2,097,152 B

  hipMemsetAsync(ws, 0, 12288, stream);  // reset protocol state every replay
  lstm_init<<<256, 256, 0, stream>>>(Wih1, bih1, bhh1, Wih2, bih2, bhh2, WT, BV);
  lstm_main<<<12 + 2 * PP, NTH, 0, stream>>>(
      x, Wih0, bih0, bhh0, Whh0, Whh1, Whh2, Wl, bl, F, hx, WT, BV, hR, xwR,
      (float*)d_out, T);
}

// Round 10
// 23059.885 us; speedup vs baseline: 1.2006x; 1.2006x over previous
//
#include <hip/hip_runtime.h>
#include <cstdint>

// ---------------- configuration ----------------
#define HDIM 250          // hidden size
#define GDIM 1000         // 4*H gate rows
#define CH   64           // chunk length (steps) for inter-WG handoff
#define PP   4            // projection WGs per layer-ring
#define NW   4            // recurrent workers per layer (unit-split, 64/64/64/58)
#define HRING 4           // h ring depth (chunks)
#define XRING 4           // xw ring depth (chunks)
#define RPAD 1024         // padded gate-row dimension
#define NTH  1024

// rec-role LDS: 2 weight quads/thread (32KB) | h dbuf (skewed) | reduce
#define HSEG 144
#define HBUF (4 * HSEG)                     // 576 B per parity
#define HB_BASE 32768
#define RED_BASE (HB_BASE + 2 * HBUF)       // 33920
#define SMEM_BYTES 92160                    // 90 KB -> 1 WG/CU (proj needs 66KB)

typedef _Float16 f16x2 __attribute__((ext_vector_type(2)));

__device__ __forceinline__ float fdot2u(uint32_t w, uint32_t h, float acc) {
#if defined(__has_builtin) && __has_builtin(__builtin_amdgcn_fdot2)
  return __builtin_amdgcn_fdot2(__builtin_bit_cast(f16x2, w),
                                __builtin_bit_cast(f16x2, h), acc, false);
#else
  f16x2 wv = __builtin_bit_cast(f16x2, w), hv = __builtin_bit_cast(f16x2, h);
  return acc + (float)wv[0] * (float)hv[0] + (float)wv[1] * (float)hv[1];
#endif
}

__device__ __forceinline__ uint32_t pkh2(float a, float b) {
  f16x2 p; p[0] = (_Float16)a; p[1] = (_Float16)b;
  return __builtin_bit_cast(uint32_t, p);
}

// pack 8 consecutive f32 weights (zero beyond HDIM / null row) into 4x fp16x2
__device__ __forceinline__ uint4 pack8q(const float* rp, int c0) {
  float c[8];
#pragma unroll
  for (int u = 0; u < 8; ++u) {
    int col = c0 + u;
    c[u] = (rp && col < HDIM) ? rp[col] : 0.f;
  }
  uint4 r;
  r.x = pkh2(c[0], c[1]); r.y = pkh2(c[2], c[3]);
  r.z = pkh2(c[4], c[5]); r.w = pkh2(c[6], c[7]);
  return r;
}

__device__ __forceinline__ float rcpf_(float x) {
#if defined(__has_builtin) && __has_builtin(__builtin_amdgcn_rcpf)
  return __builtin_amdgcn_rcpf(x);
#else
  return 1.f / x;
#endif
}
__device__ __forceinline__ float sigm(float x) {
  return rcpf_(1.f + exp2f(-1.44269504088896341f * x));
}
__device__ __forceinline__ float tanh_(float x) {
  float e = exp2f(2.88539008177792681f * x);
  return 1.f - 2.f * rcpf_(e + 1.f);
}

// DPP quad_perm: 0xB1 = swap lane^1, 0x4E = swap lane^2 (within quads)
template <int CTRL>
__device__ __forceinline__ float dppq(float v) {
  return __builtin_bit_cast(
      float, __builtin_amdgcn_update_dpp(0, __builtin_bit_cast(int, v), CTRL,
                                         0xF, 0xF, true));
}
// ds_swizzle xor-lane within 32-lane group (BitMode offset)
template <int IMM>
__device__ __forceinline__ float swz(float v) {
  return __builtin_bit_cast(
      float, __builtin_amdgcn_ds_swizzle(__builtin_bit_cast(int, v), IMM));
}

__device__ __forceinline__ void step_barrier() {
  asm volatile("s_waitcnt lgkmcnt(0)\n\ts_barrier" ::: "memory");
}

// ---------------- flags (ints, in d_ws, zeroed each launch) ----------------
#define F_HCNTW(F, li, w)  (F)[(li) * 4 + (w)]          // h chunks produced
#define F_XWCONW(F, li, w) (F)[8 + (li) * 4 + (w)]      // xw chunks consumed
#define F_HDONE(F, li, p)  (F)[16 + (li) * 4 + (p)]     // proj staged chunk
#define F_XWRDY(F, li, c)  (F)[32 + (li) * 128 + (c)]   // xw chunk ready
#define F_HXC(F, L, w)     (F)[512 + (L) * 4 + (w)]     // per-step h counter

__device__ __forceinline__ int aload(int* p) {
  return __hip_atomic_load(p, __ATOMIC_RELAXED, __HIP_MEMORY_SCOPE_AGENT);
}
__device__ __forceinline__ void arel(int* p, int v) {
  __hip_atomic_store(p, v, __ATOMIC_RELEASE, __HIP_MEMORY_SCOPE_AGENT);
}
__device__ __forceinline__ void acq_fence() {
  __builtin_amdgcn_fence(__ATOMIC_ACQUIRE, "agent");
}
__device__ __forceinline__ void spin_ge(int* p, int tgt) {
  unsigned n = 0;
  while (aload(p) < tgt) {
    __builtin_amdgcn_s_sleep(1);
    if (++n > 100000000u) return;  // hang guard; result will fail visibly
  }
}

// ---------------- init: transpose Wih1/2 -> WT[li][j][RPAD], biases ----------------
__global__ void lstm_init(const float* __restrict__ Wih1, const float* __restrict__ bih1,
                          const float* __restrict__ bhh1, const float* __restrict__ Wih2,
                          const float* __restrict__ bih2, const float* __restrict__ bhh2,
                          float* __restrict__ WT, float* __restrict__ BV) {
  int idx = blockIdx.x * blockDim.x + threadIdx.x;
  int stride = gridDim.x * blockDim.x;
  for (int i = idx; i < 2 * HDIM * RPAD; i += stride) {
    int li = i / (HDIM * RPAD);
    int rem = i - li * HDIM * RPAD;
    int j = rem / RPAD, r = rem - j * RPAD;
    const float* W = li ? Wih2 : Wih1;
    WT[i] = (r < GDIM) ? W[r * HDIM + j] : 0.f;
  }
  for (int i = idx; i < 2 * RPAD; i += stride) {
    int li = i >> 10, r = i & 1023;
    const float* bi = li ? bih2 : bih1;
    const float* bh = li ? bhh2 : bhh1;
    BV[i] = (r < GDIM) ? bi[r] + bh[r] : 0.f;
  }
}

// ---------------- main persistent kernel ----------------
// Grid = 32 blocks. Role by rem = bid%8, grp = bid/8 (XCD co-location:
// dispatch round-robins bid%8 -> XCD, so layer L's 4 workers at bids
// {L, L+8, L+16, L+24} share XCD L's L2 -> per-step h exchange is L2-local).
//   rem < 3  : rec worker, L = rem, w = grp (units [64w, 64w+64), 58 for w=3)
//   rem == 4 : proj li=0, p = grp;  rem == 5 : proj li=1, p = grp
//   else     : exit
__global__ void __launch_bounds__(NTH) lstm_main(
    const float* __restrict__ x, const float* __restrict__ Wih0,
    const float* __restrict__ bih0, const float* __restrict__ bhh0,
    const float* __restrict__ Whh0, const float* __restrict__ Whh1,
    const float* __restrict__ Whh2, const float* __restrict__ Wl,
    const float* __restrict__ bl, int* __restrict__ F, float* __restrict__ hx,
    const float* __restrict__ WT, const float* __restrict__ BV,
    float* __restrict__ hRing, float* __restrict__ xwRing,
    float* __restrict__ out, int T) {
  __shared__ __align__(16) char smem[SMEM_BYTES];
  const int tid = threadIdx.x;
  const int bid = blockIdx.x;
  const int rem = bid & 7, grp = bid >> 3;
  const int NC = T / CH;

  if (rem < 3) {
    // ================= recurrent worker =================
    const int L = rem, w = grp;
    const int sl = tid & 3;            // 64-col slice
    const int gate = (tid >> 2) & 3;   // gate row within unit
    const int lu = tid >> 4;           // local unit 0..63
    const int UW = (w < 3) ? 64 : 58;  // units this worker owns
    const int u_glob = w * 64 + lu;
    const bool uok = (lu < UW);
    const bool lead = ((tid & 15) == 0) && uok;
    const int r_abs = gate * HDIM + u_glob;  // global gate row

    const float* Whh = (L == 0) ? Whh0 : (L == 1) ? Whh1 : Whh2;
    const float* rp = uok ? (Whh + (size_t)r_abs * HDIM) : (const float*)nullptr;
    char* lw = smem + tid * 16;
#define LW(q) (lw + (size_t)(q) * (NTH * 16))

    // 8 weight quads for this row's 64-col slice: 6 in regs, 2 in LDS
    uint4 q0 = pack8q(rp, sl * 64 + 0);
    uint4 q1 = pack8q(rp, sl * 64 + 8);
    uint4 q2 = pack8q(rp, sl * 64 + 16);
    uint4 q3 = pack8q(rp, sl * 64 + 24);
    uint4 q4 = pack8q(rp, sl * 64 + 32);
    uint4 q5 = pack8q(rp, sl * 64 + 40);
    *(uint4*)LW(0) = pack8q(rp, sl * 64 + 48);
    *(uint4*)LW(1) = pack8q(rp, sl * 64 + 56);

    // L0 input-projection scalars
    float w0_ = 0.f, b0_ = 0.f;
    if (L == 0 && uok) {
      w0_ = Wih0[r_abs];
      b0_ = bih0[r_abs] + bhh0[r_abs];
    }

    // loader duty: stage 3 remote h chunks (f32 pairs -> packed fp16 LDS)
    const int lt = tid - 768;
    int cw = -1, li2 = 0;
    bool loader = false;
    if (lt >= 0 && lt < 96) {
      int idx = lt >> 5;
      li2 = lt & 31;
      cw = idx + (idx >= w ? 1 : 0);
      loader = li2 < ((cw == 3) ? 29 : 32);
    }

    // zero h double-buffer (incl. pad cols)
    for (int i = tid; i < (2 * HBUF) / 4; i += NTH)
      *(uint32_t*)(smem + HB_BASE + 4 * i) = 0u;
    __syncthreads();

    const float* xwBase = xwRing + (size_t)(L > 0 ? L - 1 : 0) * XRING * CH * RPAD;
    float* hBase = hRing + (size_t)L * HRING * CH * HDIM;
    float c_st = 0.f;

    for (int tt = 0; tt < T; ++tt) {
      const int tc = tt & (CH - 1);
      const int c = tt >> 6;
      const int p = tt & 1, ns = p ^ 1;
      if (tc == 0) {  // chunk boundary: input ready / ring backpressure
        if (tid == 0) {
          if (L > 0) spin_ge(&F_XWRDY(F, L - 1, c), 1);
          if (L < 2 && c >= HRING) {
            int cc = c - HRING;
            spin_ge(&F_HDONE(F, L, cc % PP), cc + 1);
          }
          acq_fence();
        }
        __syncthreads();
      }

      // gate input for this row (VMEM early, used after the dot)
      float xw = 0.f;
      if (uok) {
        if (L == 0) {
          xw = fmaf(x[tt], w0_, b0_);
        } else {
          const float* xp = xwBase + (size_t)(c & (XRING - 1)) * CH * RPAD +
                            (size_t)tc * RPAD;
          xw = xp[r_abs];
        }
      }

      // dot: 1 row x 64-col slice from skewed h buffer parity p
      const char* hbp = smem + HB_BASE + p * HBUF + sl * HSEG;
      float a = 0.f;
#define FD4(W_, H_)                  \
  a = fdot2u((W_).x, (H_).x, a);     \
  a = fdot2u((W_).y, (H_).y, a);     \
  a = fdot2u((W_).z, (H_).z, a);     \
  a = fdot2u((W_).w, (H_).w, a);
      { uint4 hq = *(const uint4*)(hbp + 0);  FD4(q0, hq) }
      { uint4 hq = *(const uint4*)(hbp + 16); FD4(q1, hq) }
      { uint4 hq = *(const uint4*)(hbp + 32); FD4(q2, hq) }
      { uint4 hq = *(const uint4*)(hbp + 48); FD4(q3, hq) }
      { uint4 hq = *(const uint4*)(hbp + 64); FD4(q4, hq) }
      { uint4 hq = *(const uint4*)(hbp + 80); FD4(q5, hq) }
      { uint4 hq = *(const uint4*)(hbp + 96);  uint4 t6 = *(const uint4*)LW(0); FD4(t6, hq) }
      { uint4 hq = *(const uint4*)(hbp + 112); uint4 t7 = *(const uint4*)LW(1); FD4(t7, hq) }

      // reduce over the 4 col-slices (quad butterfly), add xw
      a += dppq<0xB1>(a);
      a += dppq<0x4E>(a);
      a += xw;

      // gather the 4 gates of this unit (xor 4/8/12 within 16-lane group)
      float v4 = swz<0x101F>(a);
      float v8 = swz<0x201F>(a);
      float vc = swz<0x301F>(a);
      const float gi = (gate == 0) ? a : (gate == 1) ? v4 : (gate == 2) ? v8 : vc;
      const float gf = ((gate ^ 1) == 0) ? a : ((gate ^ 1) == 1) ? v4 : ((gate ^ 1) == 2) ? v8 : vc;
      const float gG = ((gate ^ 2) == 0) ? a : ((gate ^ 2) == 1) ? v4 : ((gate ^ 2) == 2) ? v8 : vc;
      const float go = ((gate ^ 3) == 0) ? a : ((gate ^ 3) == 1) ? v4 : ((gate ^ 3) == 2) ? v8 : vc;

      // LSTM update (redundant in all 16 lanes of the unit group)
      const float ii = sigm(gi), ff = sigm(gf), tg = tanh_(gG), oo = sigm(go);
      c_st = ff * c_st + ii * tg;
      const float hn = oo * tanh_(c_st);

      // publish own units: hRing (proj) + hx (same-XCD peers)
      if (lead) {
        if (L < 2)
          hBase[(size_t)(c & (HRING - 1)) * CH * HDIM + (size_t)tc * HDIM + u_glob] = hn;
        __hip_atomic_store((uint32_t*)&hx[(L * 2 + ns) * 256 + u_glob],
                           __builtin_bit_cast(uint32_t, hn), __ATOMIC_RELAXED,
                           __HIP_MEMORY_SCOPE_AGENT);
      }
      asm volatile("s_waitcnt vmcnt(0)" ::: "memory");
      __syncthreads();
      if (tid == 0) {
        arel(&F_HXC(F, L, w), tt + 1);
        if (tc == CH - 1) {
          if (L < 2) arel(&F_HCNTW(F, L, w), c + 1);
          if (L > 0) arel(&F_XWCONW(F, L - 1, w), c + 1);
        }
      }

      // stage h(t) into parity ns: local direct, remote via hx
      if (lead)
        *(_Float16*)(smem + HB_BASE + ns * HBUF + (u_glob >> 6) * HSEG +
                     (u_glob & 63) * 2) = (_Float16)hn;
      if (loader) {
        spin_ge(&F_HXC(F, L, cw), tt + 1);
        acq_fence();
        const float2 hv = *(const float2*)&hx[(L * 2 + ns) * 256 + 64 * cw + 2 * li2];
        *(uint32_t*)(smem + HB_BASE + ns * HBUF + cw * HSEG + 4 * li2) =
            pkh2(hv.x, hv.y);
      }
      step_barrier();
    }

    if (L == 2 && w == 0) {  // final linear on full h(T-1) (in LDS, parity T&1)
      float* red = (float*)(smem + RED_BASE);
      const int pT = T & 1;
      if (tid < HDIM) {
        float hv = (float)*(_Float16*)(smem + HB_BASE + pT * HBUF +
                                       (tid >> 6) * HSEG + (tid & 63) * 2);
        red[tid] = hv * Wl[tid];
      }
      __syncthreads();
      if (tid == 0) {
        float s = bl[0];
        for (int j = 0; j < HDIM; ++j) s += red[j];
        out[0] = s;
      }
    }
  } else if (rem == 4 || rem == 5) {
    // ================= projection role =================
    const int li = rem - 4;
    const int p = grp;
    float* ldsH = (float*)smem;  // [64][257] f32
    const int lane = tid & 63, wid = tid >> 6;
    const float* WTl = WT + (size_t)li * HDIM * RPAD;
    const float* BVl = BV + (size_t)li * RPAD;

    for (int c = p; c < NC; c += PP) {
      if (tid == 0) {
        for (int ww = 0; ww < NW; ++ww) spin_ge(&F_HCNTW(F, li, ww), c + 1);
        if (c >= XRING)
          for (int ww = 0; ww < NW; ++ww)
            spin_ge(&F_XWCONW(F, li, ww), c - XRING + 1);
        acq_fence();
      }
      __syncthreads();
      const float* hsrc = hRing + (size_t)li * HRING * CH * HDIM +
                          (size_t)(c & (HRING - 1)) * CH * HDIM;
      for (int t = wid; t < CH; t += 16)
        for (int j = lane; j < HDIM; j += 64)
          ldsH[t * 257 + j] = hsrc[t * HDIM + j];
      __syncthreads();
      if (tid == 0) arel(&F_HDONE(F, li, p), c + 1);

      float* xdst = xwRing + (size_t)li * XRING * CH * RPAD +
                    (size_t)(c & (XRING - 1)) * CH * RPAD;
      const int rb0 = wid * 64;  // 16 waves x 64 rows
      for (int grpq = 0; grpq < 8; ++grpq) {
        const int rb = rb0 + grpq * 8;
        float acc[8];
#pragma unroll
        for (int uq = 0; uq < 8; ++uq) acc[uq] = 0.f;
        const float* wp = WTl + rb;
        float4 wa4 = *(const float4*)(wp);
        float4 wb4 = *(const float4*)(wp + 4);
        for (int j = 0; j < HDIM; ++j) {
          int jn = (j + 1 < HDIM) ? j + 1 : HDIM - 1;
          float4 na = *(const float4*)(wp + (size_t)jn * RPAD);
          float4 nb = *(const float4*)(wp + (size_t)jn * RPAD + 4);
          float hj = ldsH[lane * 257 + j];
          acc[0] = fmaf(wa4.x, hj, acc[0]); acc[1] = fmaf(wa4.y, hj, acc[1]);
          acc[2] = fmaf(wa4.z, hj, acc[2]); acc[3] = fmaf(wa4.w, hj, acc[3]);
          acc[4] = fmaf(wb4.x, hj, acc[4]); acc[5] = fmaf(wb4.y, hj, acc[5]);
          acc[6] = fmaf(wb4.z, hj, acc[6]); acc[7] = fmaf(wb4.w, hj, acc[7]);
          wa4 = na; wb4 = nb;
        }
#pragma unroll
        for (int uq = 0; uq < 8; ++uq) {
          int r = rb + uq;
          if (r < GDIM) xdst[(size_t)lane * RPAD + r] = acc[uq] + BVl[r];
        }
      }
      __syncthreads();
      if (tid == 0) arel(&F_XWRDY(F, li, c), 1);
    }
  }
}

// ---------------- launch ----------------
extern "C" void kernel_launch(void* const* d_in, const int* in_sizes, int n_in,
                              void* d_out, int out_size, void* d_ws, size_t ws_size,
                              hipStream_t stream) {
  const float* x    = (const float*)d_in[0];
  const float* Wih0 = (const float*)d_in[1];
  const float* Whh0 = (const float*)d_in[2];
  const float* bih0 = (const float*)d_in[3];
  const float* bhh0 = (const float*)d_in[4];
  const float* Wih1 = (const float*)d_in[5];
  const float* Whh1 = (const float*)d_in[6];
  const float* bih1 = (const float*)d_in[7];
  const float* bhh1 = (const float*)d_in[8];
  const float* Wih2 = (const float*)d_in[9];
  const float* Whh2 = (const float*)d_in[10];
  const float* bih2 = (const float*)d_in[11];
  const float* bhh2 = (const float*)d_in[12];
  const float* Wl   = (const float*)d_in[13];
  const float* bl   = (const float*)d_in[14];
  const int T = in_sizes[0];

  char* ws = (char*)d_ws;
  int*   F   = (int*)ws;                                  // 4096 B flags
  float* hx  = (float*)(ws + 4096);                       // 6144 B h exchange
  float* WT  = (float*)(ws + 12288);                      // 2,048,000 B
  float* BV  = (float*)(ws + 12288 + 2048000);            // 8,192 B
  float* hR  = (float*)(ws + 12288 + 2048000 + 8192);     // 512,000 B
  float* xwR = (float*)(ws + 12288 + 2048000 + 8192 + 512000);  // 2,097,152 B

  hipMemsetAsync(ws, 0, 12288, stream);  // reset protocol state every replay
  lstm_init<<<256, 256, 0, stream>>>(Wih1, bih1, bhh1, Wih2, bih2, bhh2, WT, BV);
  lstm_main<<<32, NTH, 0, stream>>>(
      x, Wih0, bih0, bhh0, Whh0, Whh1, Whh2, Wl, bl, F, hx, WT, BV, hR, xwR,
      (float*)d_out, T);
}

// Round 11
// 19804.080 us; speedup vs baseline: 1.3979x; 1.1644x over previous
//
#include <hip/hip_runtime.h>
#include <cstdint>

// ---------------- configuration ----------------
#define HDIM 250          // hidden size
#define GDIM 1000         // 4*H gate rows
#define CH   64           // chunk length (steps) for inter-WG handoff
#define PP   4            // projection WGs per layer-ring
#define NW   4            // recurrent workers per layer (unit-split, 64/64/64/58)
#define HRING 4           // h ring depth (chunks)
#define XRING 4           // xw ring depth (chunks)
#define RPAD 1024         // padded gate-row dimension
#define NTH  1024

// rec-role LDS: 2 weight quads/thread (32KB) | h dbuf (skewed) | reduce
#define HSEG 144
#define HBUF (4 * HSEG)                     // 576 B per parity
#define HB_BASE 32768
#define RED_BASE (HB_BASE + 2 * HBUF)       // 33920
#define SMEM_BYTES 92160                    // 90 KB -> 1 WG/CU (proj needs 66KB)

typedef _Float16 f16x2 __attribute__((ext_vector_type(2)));

__device__ __forceinline__ float fdot2u(uint32_t w, uint32_t h, float acc) {
#if defined(__has_builtin) && __has_builtin(__builtin_amdgcn_fdot2)
  return __builtin_amdgcn_fdot2(__builtin_bit_cast(f16x2, w),
                                __builtin_bit_cast(f16x2, h), acc, false);
#else
  f16x2 wv = __builtin_bit_cast(f16x2, w), hv = __builtin_bit_cast(f16x2, h);
  return acc + (float)wv[0] * (float)hv[0] + (float)wv[1] * (float)hv[1];
#endif
}

__device__ __forceinline__ uint32_t pkh2(float a, float b) {
  f16x2 p; p[0] = (_Float16)a; p[1] = (_Float16)b;
  return __builtin_bit_cast(uint32_t, p);
}

// pack 8 consecutive f32 weights (zero beyond HDIM / null row) into 4x fp16x2
__device__ __forceinline__ uint4 pack8q(const float* rp, int c0) {
  float c[8];
#pragma unroll
  for (int u = 0; u < 8; ++u) {
    int col = c0 + u;
    c[u] = (rp && col < HDIM) ? rp[col] : 0.f;
  }
  uint4 r;
  r.x = pkh2(c[0], c[1]); r.y = pkh2(c[2], c[3]);
  r.z = pkh2(c[4], c[5]); r.w = pkh2(c[6], c[7]);
  return r;
}

__device__ __forceinline__ float rcpf_(float x) {
#if defined(__has_builtin) && __has_builtin(__builtin_amdgcn_rcpf)
  return __builtin_amdgcn_rcpf(x);
#else
  return 1.f / x;
#endif
}
__device__ __forceinline__ float sigm(float x) {
  return rcpf_(1.f + exp2f(-1.44269504088896341f * x));
}
__device__ __forceinline__ float tanh_(float x) {
  float e = exp2f(2.88539008177792681f * x);
  return 1.f - 2.f * rcpf_(e + 1.f);
}

// DPP quad_perm: 0xB1 = swap lane^1, 0x4E = swap lane^2 (within quads)
template <int CTRL>
__device__ __forceinline__ float dppq(float v) {
  return __builtin_bit_cast(
      float, __builtin_amdgcn_update_dpp(0, __builtin_bit_cast(int, v), CTRL,
                                         0xF, 0xF, true));
}
// ds_swizzle xor-lane within 32-lane group (BitMode offset)
template <int IMM>
__device__ __forceinline__ float swz(float v) {
  return __builtin_bit_cast(
      float, __builtin_amdgcn_ds_swizzle(__builtin_bit_cast(int, v), IMM));
}

__device__ __forceinline__ void step_barrier() {
  asm volatile("s_waitcnt lgkmcnt(0)\n\ts_barrier" ::: "memory");
}

// ---------------- flags (ints, in d_ws, zeroed each launch) ----------------
#define F_HCNTW(F, li, w)  (F)[(li) * 4 + (w)]          // h chunks produced
#define F_XWCONW(F, li, w) (F)[8 + (li) * 4 + (w)]      // xw chunks consumed
#define F_HDONE(F, li, p)  (F)[16 + (li) * 4 + (p)]     // proj staged chunk
#define F_XWRDY(F, li, c)  (F)[32 + (li) * 128 + (c)]   // xw chunk ready

__device__ __forceinline__ int aload(int* p) {
  return __hip_atomic_load(p, __ATOMIC_RELAXED, __HIP_MEMORY_SCOPE_AGENT);
}
__device__ __forceinline__ void arel(int* p, int v) {
  __hip_atomic_store(p, v, __ATOMIC_RELEASE, __HIP_MEMORY_SCOPE_AGENT);
}
__device__ __forceinline__ void acq_fence() {
  __builtin_amdgcn_fence(__ATOMIC_ACQUIRE, "agent");
}
__device__ __forceinline__ void spin_ge(int* p, int tgt) {
  unsigned n = 0;
  while (aload(p) < tgt) {
    __builtin_amdgcn_s_sleep(1);
    if (++n > 100000000u) return;  // hang guard; result will fail visibly
  }
}

// ---------------- init: transpose Wih1/2 -> WT[li][j][RPAD], biases ----------------
__global__ void lstm_init(const float* __restrict__ Wih1, const float* __restrict__ bih1,
                          const float* __restrict__ bhh1, const float* __restrict__ Wih2,
                          const float* __restrict__ bih2, const float* __restrict__ bhh2,
                          float* __restrict__ WT, float* __restrict__ BV) {
  int idx = blockIdx.x * blockDim.x + threadIdx.x;
  int stride = gridDim.x * blockDim.x;
  for (int i = idx; i < 2 * HDIM * RPAD; i += stride) {
    int li = i / (HDIM * RPAD);
    int rem = i - li * HDIM * RPAD;
    int j = rem / RPAD, r = rem - j * RPAD;
    const float* W = li ? Wih2 : Wih1;
    WT[i] = (r < GDIM) ? W[r * HDIM + j] : 0.f;
  }
  for (int i = idx; i < 2 * RPAD; i += stride) {
    int li = i >> 10, r = i & 1023;
    const float* bi = li ? bih2 : bih1;
    const float* bh = li ? bhh2 : bhh1;
    BV[i] = (r < GDIM) ? bi[r] + bh[r] : 0.f;
  }
}

// ---------------- main persistent kernel ----------------
// Grid = 32 blocks. Role by rem = bid%8, grp = bid/8 (XCD co-location: layer
// L's 4 workers at bids {L, L+8, L+16, L+24} share one XCD's L2).
//   rem < 3  : rec worker, L = rem, w = grp (units [64w,64w+64), 58 for w=3)
//   rem 4/5  : proj li = rem-4, p = grp
// Per-step h exchange: ONE seq-tagged 8-byte atomic per unit-pair
// (lo32 = fp16 h pair, hi32 = step seq). Consumers poll the data word itself
// -> no flag chain, no per-step vmcnt(0)/__syncthreads. Worker skew is
// causally bounded to <2 steps, so a single slot per pair is race-free.
__global__ void __launch_bounds__(NTH) lstm_main(
    const float* __restrict__ x, const float* __restrict__ Wih0,
    const float* __restrict__ bih0, const float* __restrict__ bhh0,
    const float* __restrict__ Whh0, const float* __restrict__ Whh1,
    const float* __restrict__ Whh2, const float* __restrict__ Wl,
    const float* __restrict__ bl, int* __restrict__ F,
    unsigned long long* __restrict__ hx64,
    const float* __restrict__ WT, const float* __restrict__ BV,
    float* __restrict__ hRing, float* __restrict__ xwRing,
    float* __restrict__ out, int T) {
  __shared__ __align__(16) char smem[SMEM_BYTES];
  const int tid = threadIdx.x;
  const int bid = blockIdx.x;
  const int rem = bid & 7, grp = bid >> 3;
  const int NC = T / CH;

  if (rem < 3) {
    // ================= recurrent worker =================
    const int L = rem, w = grp;
    const int sl = tid & 3;            // 64-col slice
    const int gate = (tid >> 2) & 3;   // gate row within unit
    const int lu = tid >> 4;           // local unit 0..63
    const int UW = (w < 3) ? 64 : 58;  // units this worker owns
    const int u_glob = w * 64 + lu;
    const bool uok = (lu < UW);
    const bool lead = ((tid & 15) == 0) && uok;
    const int r_abs = gate * HDIM + u_glob;  // global gate row

    const float* Whh = (L == 0) ? Whh0 : (L == 1) ? Whh1 : Whh2;
    const float* rp = uok ? (Whh + (size_t)r_abs * HDIM) : (const float*)nullptr;
    char* lw = smem + tid * 16;
#define LW(q) (lw + (size_t)(q) * (NTH * 16))

    // 8 weight quads for this row's 64-col slice: 6 in regs, 2 in LDS
    uint4 q0 = pack8q(rp, sl * 64 + 0);
    uint4 q1 = pack8q(rp, sl * 64 + 8);
    uint4 q2 = pack8q(rp, sl * 64 + 16);
    uint4 q3 = pack8q(rp, sl * 64 + 24);
    uint4 q4 = pack8q(rp, sl * 64 + 32);
    uint4 q5 = pack8q(rp, sl * 64 + 40);
    *(uint4*)LW(0) = pack8q(rp, sl * 64 + 48);
    *(uint4*)LW(1) = pack8q(rp, sl * 64 + 56);

    // L0 input-projection scalars
    float w0_ = 0.f, b0_ = 0.f;
    if (L == 0 && uok) {
      w0_ = Wih0[r_abs];
      b0_ = bih0[r_abs] + bhh0[r_abs];
    }

    // loader duty: thread handles ONE remote unit-pair (8B word)
    const int lt = tid - 768;
    int cw = -1, li2 = 0;
    bool loader = false;
    if (lt >= 0 && lt < 96) {
      int idx = lt >> 5;
      li2 = lt & 31;  // pair index within remote worker
      cw = idx + (idx >= w ? 1 : 0);
      loader = li2 < ((cw == 3) ? 29 : 32);
    }

    // zero h double-buffer (incl. pad cols)
    for (int i = tid; i < (2 * HBUF) / 4; i += NTH)
      *(uint32_t*)(smem + HB_BASE + 4 * i) = 0u;
    __syncthreads();

    const float* xwBase = xwRing + (size_t)(L > 0 ? L - 1 : 0) * XRING * CH * RPAD;
    float* hBase = hRing + (size_t)L * HRING * CH * HDIM;
    float c_st = 0.f;

    for (int tt = 0; tt < T; ++tt) {
      const int tc = tt & (CH - 1);
      const int c = tt >> 6;
      const int p = tt & 1, ns = p ^ 1;
      if (tc == 0) {  // chunk boundary: input ready / ring backpressure
        if (tid == 0) {
          if (L > 0) spin_ge(&F_XWRDY(F, L - 1, c), 1);
          if (L < 2 && c >= HRING) {
            int cc = c - HRING;
            spin_ge(&F_HDONE(F, L, cc % PP), cc + 1);
          }
          acq_fence();
        }
        __syncthreads();
      }

      // gate input for this row (VMEM early, used after the dot)
      float xw = 0.f;
      if (uok) {
        if (L == 0) {
          xw = fmaf(x[tt], w0_, b0_);
        } else {
          const float* xp = xwBase + (size_t)(c & (XRING - 1)) * CH * RPAD +
                            (size_t)tc * RPAD;
          xw = xp[r_abs];
        }
      }

      // dot: 1 row x 64-col slice from skewed h buffer parity p
      const char* hbp = smem + HB_BASE + p * HBUF + sl * HSEG;
      float a = 0.f;
#define FD4(W_, H_)                  \
  a = fdot2u((W_).x, (H_).x, a);     \
  a = fdot2u((W_).y, (H_).y, a);     \
  a = fdot2u((W_).z, (H_).z, a);     \
  a = fdot2u((W_).w, (H_).w, a);
      { uint4 hq = *(const uint4*)(hbp + 0);  FD4(q0, hq) }
      { uint4 hq = *(const uint4*)(hbp + 16); FD4(q1, hq) }
      { uint4 hq = *(const uint4*)(hbp + 32); FD4(q2, hq) }
      { uint4 hq = *(const uint4*)(hbp + 48); FD4(q3, hq) }
      { uint4 hq = *(const uint4*)(hbp + 64); FD4(q4, hq) }
      { uint4 hq = *(const uint4*)(hbp + 80); FD4(q5, hq) }
      { uint4 hq = *(const uint4*)(hbp + 96);  uint4 t6 = *(const uint4*)LW(0); FD4(t6, hq) }
      { uint4 hq = *(const uint4*)(hbp + 112); uint4 t7 = *(const uint4*)LW(1); FD4(t7, hq) }

      // reduce over the 4 col-slices (quad butterfly), add xw
      a += dppq<0xB1>(a);
      a += dppq<0x4E>(a);
      a += xw;

      // gather the 4 gates of this unit (xor 4/8/12 within 16-lane group)
      float v4 = swz<0x101F>(a);
      float v8 = swz<0x201F>(a);
      float vc = swz<0x301F>(a);
      const float gi = (gate == 0) ? a : (gate == 1) ? v4 : (gate == 2) ? v8 : vc;
      const float gf = ((gate ^ 1) == 0) ? a : ((gate ^ 1) == 1) ? v4 : ((gate ^ 1) == 2) ? v8 : vc;
      const float gG = ((gate ^ 2) == 0) ? a : ((gate ^ 2) == 1) ? v4 : ((gate ^ 2) == 2) ? v8 : vc;
      const float go = ((gate ^ 3) == 0) ? a : ((gate ^ 3) == 1) ? v4 : ((gate ^ 3) == 2) ? v8 : vc;

      // LSTM update (redundant in all 16 lanes of the unit group)
      const float ii = sigm(gi), ff = sigm(gf), tg = tanh_(gG), oo = sigm(go);
      c_st = ff * c_st + ii * tg;
      const float hn = oo * tanh_(c_st);

      // odd unit's h into the even-unit lead lane (lane^16 within 32-group)
      const float hOdd = swz<0x401F>(hn);

      if (lead) {
        if (L < 2)  // proj ring store (drained at chunk end only)
          hBase[(size_t)(c & (HRING - 1)) * CH * HDIM + (size_t)tc * HDIM + u_glob] = hn;
        // own h into next-parity local LDS
        *(_Float16*)(smem + HB_BASE + ns * HBUF + (u_glob >> 6) * HSEG +
                     (u_glob & 63) * 2) = (_Float16)hn;
        if (!(lu & 1)) {  // publish seq-tagged pair word (single 8B atomic)
          unsigned long long word =
              (unsigned long long)pkh2(hn, hOdd) |
              ((unsigned long long)(unsigned)(tt + 1) << 32);
          __hip_atomic_store(&hx64[L * 128 + (u_glob >> 1)], word,
                             __ATOMIC_RELAXED, __HIP_MEMORY_SCOPE_AGENT);
        }
      }

      // stage remote pairs: poll the data word itself (seq in hi32)
      if (loader) {
        unsigned long long* src = &hx64[L * 128 + 32 * cw + li2];
        unsigned long long word;
        unsigned n = 0;
        do {
          word = __hip_atomic_load(src, __ATOMIC_RELAXED,
                                   __HIP_MEMORY_SCOPE_AGENT);
          if (++n > 50000000u) break;  // hang guard; fails visibly
        } while ((unsigned)(word >> 32) < (unsigned)(tt + 1));
        *(uint32_t*)(smem + HB_BASE + ns * HBUF + cw * HSEG + 4 * li2) =
            (uint32_t)word;
      }

      if (tc == CH - 1) {  // chunk end: full drain then publish chunk flags
        asm volatile("s_waitcnt vmcnt(0)" ::: "memory");
        __syncthreads();
        if (tid == 0) {
          if (L < 2) arel(&F_HCNTW(F, L, w), c + 1);
          if (L > 0) arel(&F_XWCONW(F, L - 1, w), c + 1);
        }
        __syncthreads();
      } else {
        step_barrier();  // lgkm-only: LDS h stage visible to next step
      }
    }

    if (L == 2 && w == 0) {  // final linear on full h(T-1) (LDS, parity T&1)
      float* red = (float*)(smem + RED_BASE);
      const int pT = T & 1;
      if (tid < HDIM) {
        float hv = (float)*(_Float16*)(smem + HB_BASE + pT * HBUF +
                                       (tid >> 6) * HSEG + (tid & 63) * 2);
        red[tid] = hv * Wl[tid];
      }
      __syncthreads();
      if (tid == 0) {
        float s = bl[0];
        for (int j = 0; j < HDIM; ++j) s += red[j];
        out[0] = s;
      }
    }
  } else if (rem == 4 || rem == 5) {
    // ================= projection role =================
    const int li = rem - 4;
    const int p = grp;
    float* ldsH = (float*)smem;  // [64][257] f32
    const int lane = tid & 63, wid = tid >> 6;
    const float* WTl = WT + (size_t)li * HDIM * RPAD;
    const float* BVl = BV + (size_t)li * RPAD;

    for (int c = p; c < NC; c += PP) {
      if (tid == 0) {
        for (int ww = 0; ww < NW; ++ww) spin_ge(&F_HCNTW(F, li, ww), c + 1);
        if (c >= XRING)
          for (int ww = 0; ww < NW; ++ww)
            spin_ge(&F_XWCONW(F, li, ww), c - XRING + 1);
        acq_fence();
      }
      __syncthreads();
      const float* hsrc = hRing + (size_t)li * HRING * CH * HDIM +
                          (size_t)(c & (HRING - 1)) * CH * HDIM;
      for (int t = wid; t < CH; t += 16)
        for (int j = lane; j < HDIM; j += 64)
          ldsH[t * 257 + j] = hsrc[t * HDIM + j];
      __syncthreads();
      if (tid == 0) arel(&F_HDONE(F, li, p), c + 1);

      float* xdst = xwRing + (size_t)li * XRING * CH * RPAD +
                    (size_t)(c & (XRING - 1)) * CH * RPAD;
      const int rb0 = wid * 64;  // 16 waves x 64 rows
      for (int grpq = 0; grpq < 8; ++grpq) {
        const int rb = rb0 + grpq * 8;
        float acc[8];
#pragma unroll
        for (int uq = 0; uq < 8; ++uq) acc[uq] = 0.f;
        const float* wp = WTl + rb;
        float4 wa4 = *(const float4*)(wp);
        float4 wb4 = *(const float4*)(wp + 4);
        for (int j = 0; j < HDIM; ++j) {
          int jn = (j + 1 < HDIM) ? j + 1 : HDIM - 1;
          float4 na = *(const float4*)(wp + (size_t)jn * RPAD);
          float4 nb = *(const float4*)(wp + (size_t)jn * RPAD + 4);
          float hj = ldsH[lane * 257 + j];
          acc[0] = fmaf(wa4.x, hj, acc[0]); acc[1] = fmaf(wa4.y, hj, acc[1]);
          acc[2] = fmaf(wa4.z, hj, acc[2]); acc[3] = fmaf(wa4.w, hj, acc[3]);
          acc[4] = fmaf(wb4.x, hj, acc[4]); acc[5] = fmaf(wb4.y, hj, acc[5]);
          acc[6] = fmaf(wb4.z, hj, acc[6]); acc[7] = fmaf(wb4.w, hj, acc[7]);
          wa4 = na; wb4 = nb;
        }
#pragma unroll
        for (int uq = 0; uq < 8; ++uq) {
          int r = rb + uq;
          if (r < GDIM) xdst[(size_t)lane * RPAD + r] = acc[uq] + BVl[r];
        }
      }
      __syncthreads();
      if (tid == 0) arel(&F_XWRDY(F, li, c), 1);
    }
  }
}

// ---------------- launch ----------------
extern "C" void kernel_launch(void* const* d_in, const int* in_sizes, int n_in,
                              void* d_out, int out_size, void* d_ws, size_t ws_size,
                              hipStream_t stream) {
  const float* x    = (const float*)d_in[0];
  const float* Wih0 = (const float*)d_in[1];
  const float* Whh0 = (const float*)d_in[2];
  const float* bih0 = (const float*)d_in[3];
  const float* bhh0 = (const float*)d_in[4];
  const float* Wih1 = (const float*)d_in[5];
  const float* Whh1 = (const float*)d_in[6];
  const float* bih1 = (const float*)d_in[7];
  const float* bhh1 = (const float*)d_in[8];
  const float* Wih2 = (const float*)d_in[9];
  const float* Whh2 = (const float*)d_in[10];
  const float* bih2 = (const float*)d_in[11];
  const float* bhh2 = (const float*)d_in[12];
  const float* Wl   = (const float*)d_in[13];
  const float* bl   = (const float*)d_in[14];
  const int T = in_sizes[0];

  char* ws = (char*)d_ws;
  int* F = (int*)ws;                                       // 4096 B flags
  unsigned long long* hx64 = (unsigned long long*)(ws + 4096);  // 4096 B
  float* WT  = (float*)(ws + 8192);                        // 2,048,000 B
  float* BV  = (float*)(ws + 8192 + 2048000);              // 8,192 B
  float* hR  = (float*)(ws + 8192 + 2048000 + 8192);       // 512,000 B
  float* xwR = (float*)(ws + 8192 + 2048000 + 8192 + 512000);  // 2,097,152 B

  hipMemsetAsync(ws, 0, 8192, stream);  // reset protocol state every replay
  lstm_init<<<256, 256, 0, stream>>>(Wih1, bih1, bhh1, Wih2, bih2, bhh2, WT, BV);
  lstm_main<<<32, NTH, 0, stream>>>(
      x, Wih0, bih0, bhh0, Whh0, Whh1, Whh2, Wl, bl, F, hx64, WT, BV, hR, xwR,
      (float*)d_out, T);
}